// Round 3
// baseline (2423.478 us; speedup 1.0000x reference)
//
#include <hip/hip_runtime.h>

using bf16 = __bf16;
typedef __bf16 bf16x4 __attribute__((ext_vector_type(4)));
typedef __bf16 bf16x8 __attribute__((ext_vector_type(8)));
typedef float  f32x4  __attribute__((ext_vector_type(4)));

#define LDS_STRIDE 40  // 32+8 pad

// ---- dtype-dispatched access helpers (flag: 1 = inputs are fp32, 0 = bf16) --
__device__ __forceinline__ float ldf(const void* p, size_t i, int f32) {
    return f32 ? ((const float*)p)[i] : (float)((const bf16*)p)[i];
}
__device__ __forceinline__ bf16x8 ld8(const void* p, size_t i, int f32) {
    bf16x8 r;
    if (f32) {
        f32x4 a = *(const f32x4*)((const float*)p + i);
        f32x4 b = *(const f32x4*)((const float*)p + i + 4);
#pragma unroll
        for (int j = 0; j < 4; ++j) { r[j] = (bf16)a[j]; r[j + 4] = (bf16)b[j]; }
    } else {
        r = *(const bf16x8*)((const bf16*)p + i);
    }
    return r;
}
__device__ __forceinline__ void st1(void* p, size_t i, float v, int f32) {
    if (f32) ((float*)p)[i] = v;
    else     ((bf16*)p)[i] = (bf16)v;
}

// ---- detect: bf16 NaN/Inf bit patterns exist iff backing store is fp32 -----
__global__ void detect_kernel(const unsigned short* __restrict__ p, int n,
                              int* __restrict__ dflag)
{
    __shared__ int cnt;
    if (threadIdx.x == 0) cnt = 0;
    __syncthreads();
    int c = 0;
    for (int i = threadIdx.x; i < n; i += 256)
        if (((p[i] >> 7) & 0xFF) == 0xFF) ++c;
    atomicAdd(&cnt, c);
    __syncthreads();
    if (threadIdx.x == 0) *dflag = (cnt > 0) ? 1 : 0;
}

// ---- convert an input array to internal bf16 -------------------------------
__global__ void cvt_kernel(const void* __restrict__ src, bf16* __restrict__ dst,
                           int n, const int* __restrict__ dflag)
{
    const int f32 = *dflag;
    for (int i = blockIdx.x * 256 + threadIdx.x; i < n; i += gridDim.x * 256)
        dst[i] = (bf16)ldf(src, i, f32);
}

// ---- transpose input weight (KxN) -> bf16 Wt (NxK) -------------------------
__global__ void transpose_any(const void* __restrict__ W, bf16* __restrict__ Wt,
                              int K, int N, const int* __restrict__ dflag)
{
    __shared__ bf16 tile[32][33];
    const int f32 = *dflag;
    const int n0 = blockIdx.x * 32, k0 = blockIdx.y * 32;
    const int tx = threadIdx.x, ty = threadIdx.y;  // (32, 8)
#pragma unroll
    for (int i = 0; i < 4; ++i)
        tile[ty + i * 8][tx] = (bf16)ldf(W, (size_t)(k0 + ty + i * 8) * N + n0 + tx, f32);
    __syncthreads();
#pragma unroll
    for (int i = 0; i < 4; ++i)
        Wt[(size_t)(n0 + ty + i * 8) * K + k0 + tx] = tile[tx][ty + i * 8];
}

// ---------------------------------------------------------------------------
// bf16 MFMA GEMM, C = act(A @ B + bias). A: internal bf16 MxK row-major.
// B: INPUT weight (dtype-dispatched), KxN row-major, element offset boff.
// Block 256 = 4 waves 2x2, wave tile 32x32, BK=32.
// ---------------------------------------------------------------------------
template<bool RELU, bool BIAS, bool F32OUT>
__global__ __launch_bounds__(256)
void gemm_bn(const bf16* __restrict__ A, int lda,
             const void* __restrict__ B, size_t boff, int ldb,
             const bf16* __restrict__ bias,
             void* __restrict__ Cout, int ldc, int K,
             const int* __restrict__ dflag)
{
    __shared__ bf16 As[64 * LDS_STRIDE];
    __shared__ bf16 Bs[64 * LDS_STRIDE];
    const int f32 = *dflag;
    const int t = threadIdx.x;
    const int l = t & 63;
    const int quad = l >> 4, lr = l & 15;
    const int w = t >> 6, wm = w >> 1, wn = w & 1;
    const int mBlock = blockIdx.y * 64, nBlock = blockIdx.x * 64;
    const int ar = t >> 2, ac = (t & 3) * 8;      // A-stage coords
    const int kr = t >> 3, nc = (t & 7) * 8;      // B-stage coords

    f32x4 acc[2][2] = {};

    for (int k0 = 0; k0 < K; k0 += 32) {
        __syncthreads();
        *(bf16x8*)&As[ar * LDS_STRIDE + ac] =
            *(const bf16x8*)(A + (size_t)(mBlock + ar) * lda + k0 + ac);
        {
            bf16x8 v = ld8(B, boff + (size_t)(k0 + kr) * ldb + nBlock + nc, f32);
#pragma unroll
            for (int j = 0; j < 8; ++j)
                Bs[(nc + j) * LDS_STRIDE + kr] = v[j];
        }
        __syncthreads();

        bf16x8 af[2], bfr[2];
#pragma unroll
        for (int mi = 0; mi < 2; ++mi)
            af[mi] = *(const bf16x8*)&As[(wm * 32 + mi * 16 + lr) * LDS_STRIDE + quad * 8];
#pragma unroll
        for (int nj = 0; nj < 2; ++nj)
            bfr[nj] = *(const bf16x8*)&Bs[(wn * 32 + nj * 16 + lr) * LDS_STRIDE + quad * 8];
#pragma unroll
        for (int mi = 0; mi < 2; ++mi)
#pragma unroll
            for (int nj = 0; nj < 2; ++nj)
                acc[mi][nj] = __builtin_amdgcn_mfma_f32_16x16x32_bf16(
                    af[mi], bfr[nj], acc[mi][nj], 0, 0, 0);
    }

#pragma unroll
    for (int mi = 0; mi < 2; ++mi)
#pragma unroll
        for (int nj = 0; nj < 2; ++nj) {
            int col = nBlock + wn * 32 + nj * 16 + lr;
            float bv = BIAS ? (float)bias[col] : 0.f;
#pragma unroll
            for (int rr = 0; rr < 4; ++rr) {
                int row = mBlock + wm * 32 + mi * 16 + quad * 4 + rr;
                float v = acc[mi][nj][rr] + bv;
                if (RELU) v = fmaxf(v, 0.f);
                if (F32OUT) ((float*)Cout)[(size_t)row * ldc + col] = v;
                else        ((bf16*)Cout)[(size_t)row * ldc + col] = (bf16)v;
            }
        }
}

// ---------------------------------------------------------------------------
// Fused pair MLP. A[p,k] = relu(Hpart[h(p),k]+Opart[n(p),k]+b_a1[k]) on the
// fly, MFMA vs Wt_a2 (1024x2048 bf16), epilogue folds relu(.+b_a2).W_a3 into
// per-row partials -> slots[p*16 + nb*2 + wn] (deterministic, no atomics).
// Grid (8 nb, 128 mb); block 256 = 4 waves 2x2, wave tile 64x64.
// ---------------------------------------------------------------------------
__global__ __launch_bounds__(256)
void pair_gemm(const float* __restrict__ Hpart, const float* __restrict__ Opart,
               const bf16* __restrict__ b_a1, const bf16* __restrict__ Wt_a2,
               const bf16* __restrict__ b_a2, const bf16* __restrict__ w_a3,
               float* __restrict__ slots)
{
    __shared__ bf16 As[128 * LDS_STRIDE];
    __shared__ bf16 Bs[128 * LDS_STRIDE];
    const int t = threadIdx.x;
    const int l = t & 63, w = t >> 6;
    const int quad = l >> 4, lr = l & 15;
    const int wm = w >> 1, wn = w & 1;
    const int nb = blockIdx.x, mb = blockIdx.y;
    const int p0 = mb * 128;
    const int h = p0 >> 8;            // 128-row tile never crosses an h boundary
    const int nBase = p0 & 255;
    const int ar = t >> 1, ac0 = (t & 1) * 16;
    const float* Hrow = Hpart + h * 2048;
    const float* Orow = Opart + (size_t)(nBase + ar) * 2048;

    f32x4 acc[4][4] = {};

    for (int k0 = 0; k0 < 2048; k0 += 32) {
        __syncthreads();
        {
            const float* hp = Hrow + k0 + ac0;
            const float* op = Orow + k0 + ac0;
            f32x4 h0 = *(const f32x4*)(hp);
            f32x4 h1 = *(const f32x4*)(hp + 4);
            f32x4 h2 = *(const f32x4*)(hp + 8);
            f32x4 h3 = *(const f32x4*)(hp + 12);
            f32x4 o0 = *(const f32x4*)(op);
            f32x4 o1 = *(const f32x4*)(op + 4);
            f32x4 o2 = *(const f32x4*)(op + 8);
            f32x4 o3 = *(const f32x4*)(op + 12);
            bf16x8 r0, r1;
#pragma unroll
            for (int j = 0; j < 4; ++j) {
                r0[j]     = (bf16)fmaxf(h0[j] + o0[j] + (float)b_a1[k0 + ac0 + j],      0.f);
                r0[j + 4] = (bf16)fmaxf(h1[j] + o1[j] + (float)b_a1[k0 + ac0 + 4 + j],  0.f);
                r1[j]     = (bf16)fmaxf(h2[j] + o2[j] + (float)b_a1[k0 + ac0 + 8 + j],  0.f);
                r1[j + 4] = (bf16)fmaxf(h3[j] + o3[j] + (float)b_a1[k0 + ac0 + 12 + j], 0.f);
            }
            *(bf16x8*)&As[ar * LDS_STRIDE + ac0]     = r0;
            *(bf16x8*)&As[ar * LDS_STRIDE + ac0 + 8] = r1;
        }
#pragma unroll
        for (int i = 0; i < 2; ++i) {
            int idx = t + i * 256;
            int r = idx >> 2, c = (idx & 3) * 8;
            *(bf16x8*)&Bs[r * LDS_STRIDE + c] =
                *(const bf16x8*)(Wt_a2 + (size_t)(nb * 128 + r) * 2048 + k0 + c);
        }
        __syncthreads();

        bf16x8 af[4], bfr[4];
#pragma unroll
        for (int mi = 0; mi < 4; ++mi)
            af[mi] = *(const bf16x8*)&As[(wm * 64 + mi * 16 + lr) * LDS_STRIDE + quad * 8];
#pragma unroll
        for (int nj = 0; nj < 4; ++nj)
            bfr[nj] = *(const bf16x8*)&Bs[(wn * 64 + nj * 16 + lr) * LDS_STRIDE + quad * 8];
#pragma unroll
        for (int mi = 0; mi < 4; ++mi)
#pragma unroll
            for (int nj = 0; nj < 4; ++nj)
                acc[mi][nj] = __builtin_amdgcn_mfma_f32_16x16x32_bf16(
                    af[mi], bfr[nj], acc[mi][nj], 0, 0, 0);
    }

    float w3v[4], b2v[4];
#pragma unroll
    for (int nj = 0; nj < 4; ++nj) {
        int col = nb * 128 + wn * 64 + nj * 16 + lr;
        w3v[nj] = (float)w_a3[col];
        b2v[nj] = (float)b_a2[col];
    }
#pragma unroll
    for (int mi = 0; mi < 4; ++mi) {
        f32x4 rs = {0.f, 0.f, 0.f, 0.f};
#pragma unroll
        for (int nj = 0; nj < 4; ++nj)
#pragma unroll
            for (int rr = 0; rr < 4; ++rr)
                rs[rr] += fmaxf(acc[mi][nj][rr] + b2v[nj], 0.f) * w3v[nj];
#pragma unroll
        for (int off = 1; off < 16; off <<= 1) {
            rs[0] += __shfl_xor(rs[0], off);
            rs[1] += __shfl_xor(rs[1], off);
            rs[2] += __shfl_xor(rs[2], off);
            rs[3] += __shfl_xor(rs[3], off);
        }
        if (lr == 0) {
            int p = p0 + wm * 64 + mi * 16 + quad * 4;
            int slot = nb * 2 + wn;
            slots[(size_t)(p + 0) * 16 + slot] = rs[0];
            slots[(size_t)(p + 1) * 16 + slot] = rs[1];
            slots[(size_t)(p + 2) * 16 + slot] = rs[2];
            slots[(size_t)(p + 3) * 16 + slot] = rs[3];
        }
    }
}

__global__ void adj_finalize(const float* __restrict__ slots,
                             const bf16* __restrict__ b_a3, float* __restrict__ adj)
{
    int i = blockIdx.x * 256 + threadIdx.x;
    float s = (float)b_a3[0];
#pragma unroll
    for (int k = 0; k < 16; ++k) s += slots[(size_t)i * 16 + k];
    adj[i] = 1.f / (1.f + expf(-s));
}

__global__ void copy_rows(const bf16* __restrict__ src, int lds_,
                          bf16* __restrict__ dst, int ldd)
{
    int c = blockIdx.x * 256 + threadIdx.x;  // 1024 cols
    int r = blockIdx.y;
    dst[(size_t)r * ldd + c] = src[(size_t)r * lds_ + c];
}

// agg_o[h,e] = sum_n adj[h,n]*obj_msg[n,e]*(nsW[h,e]-nsW[n,e]); out stride 2048
__global__ void agg_o_kernel(const float* __restrict__ adj, const bf16* __restrict__ obj_msg,
                             const bf16* __restrict__ nsW, bf16* __restrict__ out)
{
    int e = blockIdx.x * 256 + threadIdx.x;
    int h = blockIdx.y;
    float nh = (float)nsW[h * 1024 + e];
    float s = 0.f;
    for (int n = 0; n < 256; ++n) {
        float a  = adj[h * 256 + n];
        float om = (float)obj_msg[n * 1024 + e];
        float nw = (float)nsW[n * 1024 + e];
        s += a * om * (nh - nw);
    }
    out[(size_t)h * 2048 + e] = (bf16)s;
}

// agg_h[n,e] = sum_h adj[h,n]*hum_msg[h,e]*(nsW[n,e]-nsW[h,e]); out stride 2048
__global__ void agg_h_kernel(const float* __restrict__ adj, const bf16* __restrict__ hum_msg,
                             const bf16* __restrict__ nsW, bf16* __restrict__ out)
{
    int e = blockIdx.x * 256 + threadIdx.x;
    int n = blockIdx.y;
    float nn = (float)nsW[n * 1024 + e];
    float s = 0.f;
    for (int h = 0; h < 64; ++h) {
        float a  = adj[h * 256 + n];
        float hm = (float)hum_msg[h * 1024 + e];
        float nw = (float)nsW[h * 1024 + e];
        s += a * hm * (nn - nw);
    }
    out[(size_t)n * 2048 + e] = (bf16)s;
}

// Output row r=(x,y): [h_enc[x] | nsp[x] | enc[y] | nsp[y] | prior(117)]
__global__ void out_kernel(const bf16* __restrict__ h_enc, const bf16* __restrict__ enc,
                           const bf16* __restrict__ nsp_bf, const float* __restrict__ adj,
                           const bf16* __restrict__ scores_bf, const int* __restrict__ labels,
                           const int* __restrict__ cmask, void* __restrict__ out,
                           const int* __restrict__ dflag)
{
    const int f32 = *dflag;
    const int r = blockIdx.x;
    const int x = r / 255;
    const int tt = r % 255;
    const int y = tt + (tt >= x ? 1 : 0);
    const size_t rbase = (size_t)r * 4213;
    const bf16* seg[4] = { h_enc + x * 1024, nsp_bf + x * 1024, enc + y * 1024, nsp_bf + y * 1024 };
    const int t = threadIdx.x;
#pragma unroll
    for (int k = 0; k < 4; ++k) {
        int ci = t + k * 256;            // 4-element chunk id
        int sidx = ci >> 8;
        int off = (ci & 255) * 4;
        bf16x4 v = *(const bf16x4*)(seg[sidx] + off);
        size_t d = rbase + sidx * 1024 + off;
        st1(out, d + 0, (float)v[0], f32);
        st1(out, d + 1, (float)v[1], f32);
        st1(out, d + 2, (float)v[2], f32);
        st1(out, d + 3, (float)v[3], f32);
    }
    if (t < 117) {
        float sx = (float)scores_bf[x], sy = (float)scores_bf[y];
        float lx = 8.3f / (1.f + expf(12.f - 10.f * sx));
        float ly = 8.3f / (1.f + expf(12.f - 10.f * sy));
        float a = adj[x * 256 + y];
        float m = cmask[labels[y] * 117 + t] ? 1.f : 0.f;
        st1(out, rbase + 4096 + t, a * lx * ly * m, f32);
    }
}

// ---------------------------------------------------------------------------
extern "C" void kernel_launch(void* const* d_in, const int* in_sizes, int n_in,
                              void* d_out, int out_size, void* d_ws, size_t ws_size,
                              hipStream_t stream)
{
    (void)in_sizes; (void)n_in; (void)out_size; (void)ws_size;
    const void* box    = d_in[0];
    const void* nsp    = d_in[1];
    const void* scores = d_in[2];
    const int*  labels = (const int*)d_in[3];
    const int*  cmask  = (const int*)d_in[4];
    const void* W_bh1 = d_in[5],  *b_bh1 = d_in[6];
    const void* W_bh2 = d_in[7],  *b_bh2 = d_in[8];
    const void* W_sa  = d_in[9];
    const void* W_a1  = d_in[10], *b_a1  = d_in[11];
    const void* W_a2  = d_in[12], *b_a2  = d_in[13];
    const void* W_a3  = d_in[14], *b_a3  = d_in[15];
    const void* W_hm  = d_in[16], *b_hm  = d_in[17];
    const void* W_om  = d_in[18], *b_om  = d_in[19];
    const void* W_hu  = d_in[20];
    const void* W_ou  = d_in[21];

    char* ws = (char*)d_ws;
    size_t off = 0;
    auto alloc = [&](size_t bytes) -> void* {
        off = (off + 255) & ~(size_t)255;
        void* p = ws + off;
        off += bytes;
        return p;
    };
    int*  dflag   = (int*)alloc(4);
    bf16* box_bf  = (bf16*)alloc((size_t)256 * 12544 * 2);
    bf16* nsp_bf  = (bf16*)alloc((size_t)256 * 1024 * 2);
    bf16* Wt_a2   = (bf16*)alloc((size_t)1024 * 2048 * 2);
    bf16* smalls  = (bf16*)alloc((size_t)8464 * 2);
    bf16* sb_bh1 = smalls,        *sb_bh2 = smalls + 1024;
    bf16* sb_om  = smalls + 2048, *sb_hm  = smalls + 3072;
    bf16* sb_a1  = smalls + 4096, *sb_a2  = smalls + 6144;
    bf16* sw_a3  = smalls + 7168, *sb_a3  = smalls + 8192;
    bf16* sscore = smalls + 8208;
    bf16* t0      = (bf16*)alloc((size_t)256 * 1024 * 2);
    bf16* enc     = (bf16*)alloc((size_t)256 * 1024 * 2);
    bf16* nsW     = (bf16*)alloc((size_t)256 * 1024 * 2);
    bf16* h_enc   = (bf16*)alloc((size_t)64 * 1024 * 2);
    bf16* hf      = (bf16*)alloc((size_t)64 * 2048 * 2);
    bf16* of      = (bf16*)alloc((size_t)256 * 2048 * 2);
    float* Hpart  = (float*)alloc((size_t)64 * 2048 * 4);
    float* Opart  = (float*)alloc((size_t)256 * 2048 * 4);
    float* slots  = (float*)alloc((size_t)16384 * 16 * 4);
    float* adj    = (float*)alloc((size_t)16384 * 4);
    bf16* obj_msg = (bf16*)alloc((size_t)256 * 1024 * 2);
    bf16* hu_in   = (bf16*)alloc((size_t)64 * 2048 * 2);
    bf16* hum_msg = (bf16*)alloc((size_t)64 * 1024 * 2);
    bf16* ou_in   = (bf16*)alloc((size_t)256 * 2048 * 2);

    // 1) dtype probe (fp32 backing store injects bf16-NaN patterns; bf16 cannot)
    detect_kernel<<<1, 256, 0, stream>>>((const unsigned short*)box, 524288, dflag);

    // 2) convert inputs used as A-operands / epilogue scalars to internal bf16
    auto cvt = [&](const void* s, bf16* d, int n) {
        int g = (n + 255) / 256; if (g > 4096) g = 4096;
        cvt_kernel<<<g, 256, 0, stream>>>(s, d, n, dflag);
    };
    cvt(box, box_bf, 256 * 12544);
    cvt(nsp, nsp_bf, 256 * 1024);
    cvt(b_bh1, sb_bh1, 1024);  cvt(b_bh2, sb_bh2, 1024);
    cvt(b_om,  sb_om,  1024);  cvt(b_hm,  sb_hm,  1024);
    cvt(b_a1,  sb_a1,  2048);  cvt(b_a2,  sb_a2,  1024);
    cvt(W_a3,  sw_a3,  1024);  cvt(b_a3,  sb_a3,  1);
    cvt(scores, sscore, 256);

    // 3) W_a2 -> bf16 transposed (hot operand of pair_gemm, re-read 128x)
    transpose_any<<<dim3(1024 / 32, 2048 / 32), dim3(32, 8), 0, stream>>>(
        W_a2, Wt_a2, 2048, 1024, dflag);

    // 4) enc = relu(relu(box@W_bh1+b)@W_bh2+b); nsW = nsp@W_sa
    gemm_bn<true, true, false><<<dim3(16, 4), 256, 0, stream>>>(
        box_bf, 12544, W_bh1, 0, 1024, sb_bh1, t0, 1024, 12544, dflag);
    gemm_bn<true, true, false><<<dim3(16, 4), 256, 0, stream>>>(
        t0, 1024, W_bh2, 0, 1024, sb_bh2, enc, 1024, 1024, dflag);
    gemm_bn<false, false, false><<<dim3(16, 4), 256, 0, stream>>>(
        nsp_bf, 1024, W_sa, 0, 1024, nullptr, nsW, 1024, 1024, dflag);
    copy_rows<<<dim3(4, 64), 256, 0, stream>>>(enc, 1024, h_enc, 1024);

    for (int it = 0; it < 2; ++it) {
        copy_rows<<<dim3(4, 64), 256, 0, stream>>>(h_enc, 1024, hf, 2048);
        copy_rows<<<dim3(4, 64), 256, 0, stream>>>(nsp_bf, 1024, hf + 1024, 2048);
        copy_rows<<<dim3(4, 256), 256, 0, stream>>>(enc, 1024, of, 2048);
        copy_rows<<<dim3(4, 256), 256, 0, stream>>>(nsp_bf, 1024, of + 1024, 2048);
        // Hpart = hf @ W_a1[:2048,:], Opart = of @ W_a1[2048:,:]   (fp32 out)
        gemm_bn<false, false, true><<<dim3(32, 1), 256, 0, stream>>>(
            hf, 2048, W_a1, 0, 2048, nullptr, Hpart, 2048, 2048, dflag);
        gemm_bn<false, false, true><<<dim3(32, 4), 256, 0, stream>>>(
            of, 2048, W_a1, (size_t)2048 * 2048, 2048, nullptr, Opart, 2048, 2048, dflag);
        // adj = sigmoid(pair MLP)   (deterministic slots, no atomics)
        pair_gemm<<<dim3(8, 128), 256, 0, stream>>>(Hpart, Opart, sb_a1, Wt_a2, sb_a2, sw_a3, slots);
        adj_finalize<<<dim3(64), 256, 0, stream>>>(slots, sb_a3, adj);
        // obj_msg = relu(enc @ W_om + b)
        gemm_bn<true, true, false><<<dim3(16, 4), 256, 0, stream>>>(
            enc, 1024, W_om, 0, 1024, sb_om, obj_msg, 1024, 1024, dflag);
        // h_enc = [h_enc | agg_o] @ W_hu
        copy_rows<<<dim3(4, 64), 256, 0, stream>>>(h_enc, 1024, hu_in, 2048);
        agg_o_kernel<<<dim3(4, 64), 256, 0, stream>>>(adj, obj_msg, nsW, hu_in + 1024);
        gemm_bn<false, false, false><<<dim3(16, 1), 256, 0, stream>>>(
            hu_in, 2048, W_hu, 0, 1024, nullptr, h_enc, 1024, 2048, dflag);
        // hum_msg = relu(h_enc @ W_hm + b)
        gemm_bn<true, true, false><<<dim3(16, 1), 256, 0, stream>>>(
            h_enc, 1024, W_hm, 0, 1024, sb_hm, hum_msg, 1024, 1024, dflag);
        // enc = [enc | agg_h] @ W_ou
        copy_rows<<<dim3(4, 256), 256, 0, stream>>>(enc, 1024, ou_in, 2048);
        agg_h_kernel<<<dim3(4, 256), 256, 0, stream>>>(adj, hum_msg, nsW, ou_in + 1024);
        gemm_bn<false, false, false><<<dim3(16, 4), 256, 0, stream>>>(
            ou_in, 2048, W_ou, 0, 1024, nullptr, enc, 1024, 2048, dflag);
    }

    out_kernel<<<dim3(16320), 256, 0, stream>>>(
        h_enc, enc, nsp_bf, adj, sscore, labels, cmask, d_out, dflag);
}